// Round 1
// baseline (249.924 us; speedup 1.0000x reference)
//
#include <hip/hip_runtime.h>
#include <hip/hip_bf16.h>
#include <cstdint>
#include <cstddef>

typedef __attribute__((ext_vector_type(8))) short bf16x8;
typedef __attribute__((ext_vector_type(4))) float f32x4;

#define AS1 __attribute__((address_space(1)))
#define AS3 __attribute__((address_space(3)))

__device__ __forceinline__ void gload_lds16(const void* g, void* l) {
  __builtin_amdgcn_global_load_lds((const AS1 void*)g, (AS3 void*)l, 16, 0, 0);
}

__device__ __forceinline__ unsigned short f2bf(float x) {
  __hip_bfloat16 h = __float2bfloat16(x);
  return __builtin_bit_cast(unsigned short, h);
}

// ============ 1. f32 -> bf16 convert (float4 loads, grid-stride) ============
__global__ __launch_bounds__(256) void k_cvt_bf16(const float* __restrict__ in,
                                                  unsigned short* __restrict__ out,
                                                  int n4) {
  int i = blockIdx.x * 256 + threadIdx.x;
  const int stride = gridDim.x * 256;
  for (; i < n4; i += stride) {
    float4 v = reinterpret_cast<const float4*>(in)[i];
    ushort4 o;
    o.x = f2bf(v.x); o.y = f2bf(v.y); o.z = f2bf(v.z); o.w = f2bf(v.w);
    reinterpret_cast<ushort4*>(out)[i] = o;
  }
}

// ============ 2. RoPE cos/sin tables [2048][64] ============
// head_dim=128 -> dt=44 (22 freqs), dh=42 (21), dw=42 (21); n = t*H*W + h*W + w
__global__ __launch_bounds__(256) void k_rope_tab(float* __restrict__ cosT,
                                                  float* __restrict__ sinT,
                                                  const int* __restrict__ hdim,
                                                  const int* __restrict__ wdim) {
  int idx = blockIdx.x * 256 + threadIdx.x;
  if (idx >= 2048 * 64) return;
  const int n = idx >> 6, j = idx & 63;
  const int H = *hdim, W = *wdim;
  const int w = n % W;
  const int rem = n / W;
  const int h = rem % H;
  const int t = rem / H;
  float pos, i2, d;
  if (j < 22)      { pos = (float)t; i2 = (float)(2 * j);        d = 44.f; }
  else if (j < 43) { pos = (float)h; i2 = (float)(2 * (j - 22)); d = 42.f; }
  else             { pos = (float)w; i2 = (float)(2 * (j - 43)); d = 42.f; }
  const float ang = pos * powf(10000.0f, -i2 / d);
  cosT[idx] = cosf(ang);
  sinT[idx] = sinf(ang);
}

// ============ 3. bf16 GEMM, B^T layout: C[M][N] = A[M][K] * B[N][K]^T + bias[N]
// m97 structure: 128x128 tile, BK=32, global_load_lds w16, 16x16x32 MFMA, 4x4 acc/wave
__global__ __launch_bounds__(256) void k_gemm_bt(const unsigned short* __restrict__ A,
                                                 const unsigned short* __restrict__ B,
                                                 const float* __restrict__ bias,
                                                 float* __restrict__ C,
                                                 int M, int N, int K) {
  __shared__ __align__(16) unsigned short As[128 * 32];
  __shared__ __align__(16) unsigned short Bs[128 * 32];
  const int lane = threadIdx.x & 63;
  const int wid  = threadIdx.x >> 6;
  const int wr = wid >> 1, wc = wid & 1;
  const int rowA0 = blockIdx.y * 128;
  const int rowB0 = blockIdx.x * 128;

  f32x4 acc[4][4];
#pragma unroll
  for (int i = 0; i < 4; ++i)
#pragma unroll
    for (int j = 0; j < 4; ++j) acc[i][j] = (f32x4){0.f, 0.f, 0.f, 0.f};

  for (int kt = 0; kt < K; kt += 32) {
#pragma unroll
    for (int i = 0; i < 2; ++i) {
      const int c = i * 4 + wid;           // 8 chunks of 1024B per 8KB tile
      const int off = c * 1024 + lane * 16;
      const int row = off >> 6;            // 64B per row of 32 bf16
      const int col = (off & 63) >> 1;
      gload_lds16(A + (size_t)(rowA0 + row) * K + kt + col, (char*)As + c * 1024);
      gload_lds16(B + (size_t)(rowB0 + row) * K + kt + col, (char*)Bs + c * 1024);
    }
    __syncthreads();
    bf16x8 af[4], bfr[4];
#pragma unroll
    for (int mi = 0; mi < 4; ++mi)
      af[mi] = *reinterpret_cast<const bf16x8*>(
          &As[(wr * 64 + mi * 16 + (lane & 15)) * 32 + (lane >> 4) * 8]);
#pragma unroll
    for (int ni = 0; ni < 4; ++ni)
      bfr[ni] = *reinterpret_cast<const bf16x8*>(
          &Bs[(wc * 64 + ni * 16 + (lane & 15)) * 32 + (lane >> 4) * 8]);
#pragma unroll
    for (int mi = 0; mi < 4; ++mi)
#pragma unroll
      for (int ni = 0; ni < 4; ++ni)
        acc[mi][ni] = __builtin_amdgcn_mfma_f32_16x16x32_bf16(af[mi], bfr[ni], acc[mi][ni], 0, 0, 0);
    __syncthreads();
  }

#pragma unroll
  for (int mi = 0; mi < 4; ++mi)
#pragma unroll
    for (int ni = 0; ni < 4; ++ni) {
      const int col = rowB0 + wc * 64 + ni * 16 + (lane & 15);
      const float b = bias[col];
#pragma unroll
      for (int j = 0; j < 4; ++j) {
        const int row = rowA0 + wr * 64 + mi * 16 + (lane >> 4) * 4 + j;
        C[(size_t)row * N + col] = acc[mi][ni][j] + b;
      }
    }
}

// ============ 4a. q/k: RMSNorm (fp32) + RoPE + (q: fold softmax scale) -> bf16 [h][n][d]
__global__ __launch_bounds__(256) void k_qk_post(const float* __restrict__ qkv,
                                                 const float* __restrict__ qw,
                                                 const float* __restrict__ kw,
                                                 const float* __restrict__ cosT,
                                                 const float* __restrict__ sinT,
                                                 unsigned short* __restrict__ qo,
                                                 unsigned short* __restrict__ ko) {
  const int lane = threadIdx.x & 63;
  const int wid = threadIdx.x >> 6;
  const int pair = blockIdx.x * 4 + wid;  // (n,h)
  const int n = pair >> 4, h = pair & 15;
  const float c = cosT[n * 64 + lane];
  const float s = sinT[n * 64 + lane];
#pragma unroll
  for (int sq = 0; sq < 2; ++sq) {
    const float* src = qkv + (size_t)n * 6144 + sq * 2048 + h * 128;
    float2 v = reinterpret_cast<const float2*>(src)[lane];  // d = 2*lane, 2*lane+1
    float ss = v.x * v.x + v.y * v.y;
#pragma unroll
    for (int m = 1; m < 64; m <<= 1) ss += __shfl_xor(ss, m, 64);
    const float r = rsqrtf(ss * (1.0f / 128.0f) + 1e-6f);
    float2 wv = reinterpret_cast<const float2*>(sq == 0 ? qw : kw)[lane];
    const float xr = v.x * r * wv.x;
    const float xi = v.y * r * wv.y;
    float orr = xr * c - xi * s;
    float oi  = xr * s + xi * c;
    if (sq == 0) { orr *= 0.08838834764831845f; oi *= 0.08838834764831845f; }
    unsigned short* dst = (sq == 0 ? qo : ko) + ((size_t)h * 2048 + n) * 128 + 2 * lane;
    const unsigned int pk = (unsigned int)f2bf(orr) | ((unsigned int)f2bf(oi) << 16);
    *reinterpret_cast<unsigned int*>(dst) = pk;
  }
}

// ============ 4b. v transpose: qkv v-block fp32 -> vt[h][d][n] bf16 (LDS-tiled)
__global__ __launch_bounds__(256) void k_v_tr(const float* __restrict__ qkv,
                                              unsigned short* __restrict__ vt) {
  __shared__ __align__(16) unsigned short tile[64][130];  // +2 pad breaks bank aliasing
  const int h = blockIdx.y;
  const int n0 = blockIdx.x * 64;
  const int t = threadIdx.x;
  {
    const int row = t >> 2;
    const int c0 = (t & 3) * 32;
    const float* src = qkv + (size_t)(n0 + row) * 6144 + 4096 + h * 128 + c0;
#pragma unroll
    for (int j = 0; j < 32; j += 4) {
      float4 v = reinterpret_cast<const float4*>(src + j)[0];
      tile[row][c0 + j + 0] = f2bf(v.x);
      tile[row][c0 + j + 1] = f2bf(v.y);
      tile[row][c0 + j + 2] = f2bf(v.z);
      tile[row][c0 + j + 3] = f2bf(v.w);
    }
  }
  __syncthreads();
  {
    const int d = t >> 1;
    const int nc = (t & 1) * 32;
    unsigned short* dst = vt + ((size_t)h * 128 + d) * 2048 + n0 + nc;
#pragma unroll
    for (int j = 0; j < 32; j += 8) {
      bf16x8 o;
#pragma unroll
      for (int jj = 0; jj < 8; ++jj) o[jj] = (short)tile[nc + j + jj][d];
      *reinterpret_cast<bf16x8*>(dst + j) = o;
    }
  }
}

// ============ 5. flash attention: 4 waves x 16 q-rows, 64-key tiles, online softmax
// K_lds [64][128] and Vt_lds [128][64] XOR-swizzled via pre-swizzled global source.
__global__ __launch_bounds__(256) void k_fattn(const unsigned short* __restrict__ q,
                                               const unsigned short* __restrict__ k,
                                               const unsigned short* __restrict__ vt,
                                               unsigned short* __restrict__ out) {
  __shared__ __align__(16) unsigned short Ks[64 * 128];
  __shared__ __align__(16) unsigned short Vs[128 * 64];
  __shared__ __align__(16) unsigned short Ps[4][16][72];  // 72 = 64 + 8 pad
  const int lane = threadIdx.x & 63;
  const int wid = threadIdx.x >> 6;
  const int h = blockIdx.x & 15;   // XCD = bx%8 -> head pinned to one XCD's L2
  const int qb = blockIdx.x >> 4;
  const int q0 = qb * 64 + wid * 16;

  bf16x8 qf[4];
  {
    const unsigned short* qp = q + ((size_t)h * 2048 + q0 + (lane & 15)) * 128 + (lane >> 4) * 8;
#pragma unroll
    for (int kc = 0; kc < 4; ++kc) qf[kc] = *reinterpret_cast<const bf16x8*>(qp + kc * 32);
  }
  f32x4 O[8];
#pragma unroll
  for (int i = 0; i < 8; ++i) O[i] = (f32x4){0.f, 0.f, 0.f, 0.f};
  float mrow[4] = {-1e30f, -1e30f, -1e30f, -1e30f};
  float lrow[4] = {0.f, 0.f, 0.f, 0.f};

  for (int kt = 0; kt < 32; ++kt) {
#pragma unroll
    for (int i = 0; i < 4; ++i) {
      const int c = i * 4 + wid;           // 16 chunks of 1024B per 16KB tile
      const int off = c * 1024 + lane * 16;
      // K tile: rows of 256B, physical off receives logical col (off&255)^((row&7)<<4)
      const int krow = off >> 8;
      const int kcb = (off & 255) ^ ((krow & 7) << 4);
      gload_lds16(k + ((size_t)h * 2048 + kt * 64 + krow) * 128 + (kcb >> 1),
                  (char*)Ks + c * 1024);
      // Vt tile: rows of 128B
      const int vrow = off >> 7;
      const int vcb = (off & 127) ^ ((vrow & 7) << 4);
      gload_lds16(vt + ((size_t)h * 128 + vrow) * 2048 + kt * 64 + (vcb >> 1),
                  (char*)Vs + c * 1024);
    }
    __syncthreads();

    // S = Q K^T  (scale pre-folded into q)
    f32x4 sf[4];
#pragma unroll
    for (int ni = 0; ni < 4; ++ni) {
      f32x4 a = (f32x4){0.f, 0.f, 0.f, 0.f};
      const int key = ni * 16 + (lane & 15);
#pragma unroll
      for (int kc = 0; kc < 4; ++kc) {
        const int db = (kc * 64 + (lane >> 4) * 16) ^ ((key & 7) << 4);
        bf16x8 b = *reinterpret_cast<const bf16x8*>((const char*)Ks + key * 256 + db);
        a = __builtin_amdgcn_mfma_f32_16x16x32_bf16(qf[kc], b, a, 0, 0, 0);
      }
      sf[ni] = a;
    }

    // online softmax: rows live in reg j per 16-lane group; cols across lane&15
    float alpha[4];
#pragma unroll
    for (int j = 0; j < 4; ++j) {
      float mt = fmaxf(fmaxf(sf[0][j], sf[1][j]), fmaxf(sf[2][j], sf[3][j]));
#pragma unroll
      for (int m = 1; m < 16; m <<= 1) mt = fmaxf(mt, __shfl_xor(mt, m, 64));
      const float mn = fmaxf(mrow[j], mt);
      alpha[j] = __expf(mrow[j] - mn);
      mrow[j] = mn;
      float rs = 0.f;
#pragma unroll
      for (int ni = 0; ni < 4; ++ni) {
        const float p = __expf(sf[ni][j] - mn);
        sf[ni][j] = p;
        rs += p;
      }
#pragma unroll
      for (int m = 1; m < 16; m <<= 1) rs += __shfl_xor(rs, m, 64);
      lrow[j] = lrow[j] * alpha[j] + rs;
    }
#pragma unroll
    for (int dc = 0; dc < 8; ++dc)
#pragma unroll
      for (int j = 0; j < 4; ++j) O[dc][j] *= alpha[j];

    // P (bf16) through per-wave padded LDS to reach MFMA A-layout
#pragma unroll
    for (int ni = 0; ni < 4; ++ni)
#pragma unroll
      for (int j = 0; j < 4; ++j)
        Ps[wid][(lane >> 4) * 4 + j][ni * 16 + (lane & 15)] = f2bf(sf[ni][j]);

    bf16x8 pa[2];
#pragma unroll
    for (int ks = 0; ks < 2; ++ks)
      pa[ks] = *reinterpret_cast<const bf16x8*>(&Ps[wid][lane & 15][ks * 32 + (lane >> 4) * 8]);

    // O += P * V   (B-operand from swizzled Vt rows)
#pragma unroll
    for (int dc = 0; dc < 8; ++dc) {
      const int d = dc * 16 + (lane & 15);
#pragma unroll
      for (int ks = 0; ks < 2; ++ks) {
        const int kb = (ks * 64 + (lane >> 4) * 16) ^ ((d & 7) << 4);
        bf16x8 b = *reinterpret_cast<const bf16x8*>((const char*)Vs + d * 128 + kb);
        O[dc] = __builtin_amdgcn_mfma_f32_16x16x32_bf16(pa[ks], b, O[dc], 0, 0, 0);
      }
    }
    __syncthreads();
  }

#pragma unroll
  for (int dc = 0; dc < 8; ++dc)
#pragma unroll
    for (int j = 0; j < 4; ++j) {
      const int row = q0 + (lane >> 4) * 4 + j;
      const int col = h * 128 + dc * 16 + (lane & 15);
      out[(size_t)row * 2048 + col] = f2bf(O[dc][j] / lrow[j]);
    }
}

extern "C" void kernel_launch(void* const* d_in, const int* in_sizes, int n_in,
                              void* d_out, int out_size, void* d_ws, size_t ws_size,
                              hipStream_t stream) {
  (void)in_sizes; (void)n_in; (void)out_size; (void)ws_size;
  const float* x      = (const float*)d_in[0];
  const float* qkv_w  = (const float*)d_in[1];
  const float* qkv_b  = (const float*)d_in[2];
  const float* proj_w = (const float*)d_in[3];
  const float* proj_b = (const float*)d_in[4];
  const float* q_nw   = (const float*)d_in[5];
  const float* k_nw   = (const float*)d_in[6];
  const int* h_dim    = (const int*)d_in[8];
  const int* w_dim    = (const int*)d_in[9];
  float* out = (float*)d_out;

  char* ws = (char*)d_ws;
  size_t off = 0;
  auto carve = [&](size_t bytes) -> void* {
    void* p = ws + off;
    off += (bytes + 255) & ~(size_t)255;
    return p;
  };
  unsigned short* x_bf   = (unsigned short*)carve(2048ull * 2048 * 2);
  unsigned short* w1_bf  = (unsigned short*)carve(6144ull * 2048 * 2);
  unsigned short* w2_bf  = (unsigned short*)carve(2048ull * 2048 * 2);
  float*          qkvf   = (float*)carve(2048ull * 6144 * 4);
  unsigned short* q_bf   = (unsigned short*)carve(16ull * 2048 * 128 * 2);
  unsigned short* k_bf   = (unsigned short*)carve(16ull * 2048 * 128 * 2);
  unsigned short* vt_bf  = (unsigned short*)carve(16ull * 2048 * 128 * 2);
  unsigned short* att_bf = (unsigned short*)carve(2048ull * 2048 * 2);
  float*          cosT   = (float*)carve(2048ull * 64 * 4);
  float*          sinT   = (float*)carve(2048ull * 64 * 4);

  hipLaunchKernelGGL(k_cvt_bf16, dim3(2048), dim3(256), 0, stream, x, x_bf, 2048 * 2048 / 4);
  hipLaunchKernelGGL(k_cvt_bf16, dim3(2048), dim3(256), 0, stream, qkv_w, w1_bf, 6144 * 2048 / 4);
  hipLaunchKernelGGL(k_cvt_bf16, dim3(2048), dim3(256), 0, stream, proj_w, w2_bf, 2048 * 2048 / 4);
  hipLaunchKernelGGL(k_rope_tab, dim3(512), dim3(256), 0, stream, cosT, sinT, h_dim, w_dim);
  hipLaunchKernelGGL(k_gemm_bt, dim3(48, 16), dim3(256), 0, stream,
                     x_bf, w1_bf, qkv_b, qkvf, 2048, 6144, 2048);
  hipLaunchKernelGGL(k_qk_post, dim3(8192), dim3(256), 0, stream,
                     qkvf, q_nw, k_nw, cosT, sinT, q_bf, k_bf);
  hipLaunchKernelGGL(k_v_tr, dim3(32, 16), dim3(256), 0, stream, qkvf, vt_bf);
  hipLaunchKernelGGL(k_fattn, dim3(512), dim3(256), 0, stream, q_bf, k_bf, vt_bf, att_bf);
  hipLaunchKernelGGL(k_gemm_bt, dim3(16, 16), dim3(256), 0, stream,
                     att_bf, w2_bf, proj_b, out, 2048, 2048, 2048);
}

// Round 2
// 216.629 us; speedup vs baseline: 1.1537x; 1.1537x over previous
//
#include <hip/hip_runtime.h>
#include <hip/hip_bf16.h>
#include <cstdint>
#include <cstddef>

typedef __attribute__((ext_vector_type(8))) short bf16x8;
typedef __attribute__((ext_vector_type(4))) float f32x4;

#define AS1 __attribute__((address_space(1)))
#define AS3 __attribute__((address_space(3)))

__device__ __forceinline__ void gload_lds16(const void* g, void* l) {
  __builtin_amdgcn_global_load_lds((const AS1 void*)g, (AS3 void*)l, 16, 0, 0);
}

__device__ __forceinline__ unsigned short f2bf(float x) {
  __hip_bfloat16 h = __float2bfloat16(x);
  return __builtin_bit_cast(unsigned short, h);
}

// ============ 1. f32 -> bf16 convert (float4 loads, grid-stride) ============
__global__ __launch_bounds__(256) void k_cvt_bf16(const float* __restrict__ in,
                                                  unsigned short* __restrict__ out,
                                                  int n4) {
  int i = blockIdx.x * 256 + threadIdx.x;
  const int stride = gridDim.x * 256;
  for (; i < n4; i += stride) {
    float4 v = reinterpret_cast<const float4*>(in)[i];
    ushort4 o;
    o.x = f2bf(v.x); o.y = f2bf(v.y); o.z = f2bf(v.z); o.w = f2bf(v.w);
    reinterpret_cast<ushort4*>(out)[i] = o;
  }
}

// ============ 2. RoPE cos/sin tables [2048][64] ============
__global__ __launch_bounds__(256) void k_rope_tab(float* __restrict__ cosT,
                                                  float* __restrict__ sinT,
                                                  const int* __restrict__ hdim,
                                                  const int* __restrict__ wdim) {
  int idx = blockIdx.x * 256 + threadIdx.x;
  if (idx >= 2048 * 64) return;
  const int n = idx >> 6, j = idx & 63;
  const int H = *hdim, W = *wdim;
  const int w = n % W;
  const int rem = n / W;
  const int h = rem % H;
  const int t = rem / H;
  float pos, i2, d;
  if (j < 22)      { pos = (float)t; i2 = (float)(2 * j);        d = 44.f; }
  else if (j < 43) { pos = (float)h; i2 = (float)(2 * (j - 22)); d = 42.f; }
  else             { pos = (float)w; i2 = (float)(2 * (j - 43)); d = 42.f; }
  const float ang = pos * powf(10000.0f, -i2 / d);
  cosT[idx] = cosf(ang);
  sinT[idx] = sinf(ang);
}

// ============ 3. bf16 GEMM, B^T layout (m97 structure, known ~900 TF ceiling) ====
__global__ __launch_bounds__(256) void k_gemm_bt(const unsigned short* __restrict__ A,
                                                 const unsigned short* __restrict__ B,
                                                 const float* __restrict__ bias,
                                                 float* __restrict__ C,
                                                 int M, int N, int K) {
  __shared__ __align__(16) unsigned short As[128 * 32];
  __shared__ __align__(16) unsigned short Bs[128 * 32];
  const int lane = threadIdx.x & 63;
  const int wid  = threadIdx.x >> 6;
  const int wr = wid >> 1, wc = wid & 1;
  const int rowA0 = blockIdx.y * 128;
  const int rowB0 = blockIdx.x * 128;

  f32x4 acc[4][4];
#pragma unroll
  for (int i = 0; i < 4; ++i)
#pragma unroll
    for (int j = 0; j < 4; ++j) acc[i][j] = (f32x4){0.f, 0.f, 0.f, 0.f};

  for (int kt = 0; kt < K; kt += 32) {
#pragma unroll
    for (int i = 0; i < 2; ++i) {
      const int c = i * 4 + wid;
      const int off = c * 1024 + lane * 16;
      const int row = off >> 6;
      const int col = (off & 63) >> 1;
      gload_lds16(A + (size_t)(rowA0 + row) * K + kt + col, (char*)As + c * 1024);
      gload_lds16(B + (size_t)(rowB0 + row) * K + kt + col, (char*)Bs + c * 1024);
    }
    __syncthreads();
    bf16x8 af[4], bfr[4];
#pragma unroll
    for (int mi = 0; mi < 4; ++mi)
      af[mi] = *reinterpret_cast<const bf16x8*>(
          &As[(wr * 64 + mi * 16 + (lane & 15)) * 32 + (lane >> 4) * 8]);
#pragma unroll
    for (int ni = 0; ni < 4; ++ni)
      bfr[ni] = *reinterpret_cast<const bf16x8*>(
          &Bs[(wc * 64 + ni * 16 + (lane & 15)) * 32 + (lane >> 4) * 8]);
#pragma unroll
    for (int mi = 0; mi < 4; ++mi)
#pragma unroll
      for (int ni = 0; ni < 4; ++ni)
        acc[mi][ni] = __builtin_amdgcn_mfma_f32_16x16x32_bf16(af[mi], bfr[ni], acc[mi][ni], 0, 0, 0);
    __syncthreads();
  }

#pragma unroll
  for (int mi = 0; mi < 4; ++mi)
#pragma unroll
    for (int ni = 0; ni < 4; ++ni) {
      const int col = rowB0 + wc * 64 + ni * 16 + (lane & 15);
      const float b = bias[col];
#pragma unroll
      for (int j = 0; j < 4; ++j) {
        const int row = rowA0 + wr * 64 + mi * 16 + (lane >> 4) * 4 + j;
        C[(size_t)row * N + col] = acc[mi][ni][j] + b;
      }
    }
}

// ============ 4a. q/k: RMSNorm + RoPE + (q: fold softmax scale) -> bf16 [h][n][d]
__global__ __launch_bounds__(256) void k_qk_post(const float* __restrict__ qkv,
                                                 const float* __restrict__ qw,
                                                 const float* __restrict__ kw,
                                                 const float* __restrict__ cosT,
                                                 const float* __restrict__ sinT,
                                                 unsigned short* __restrict__ qo,
                                                 unsigned short* __restrict__ ko) {
  const int lane = threadIdx.x & 63;
  const int wid = threadIdx.x >> 6;
  const int pair = blockIdx.x * 4 + wid;  // (n,h)
  const int n = pair >> 4, h = pair & 15;
  const float c = cosT[n * 64 + lane];
  const float s = sinT[n * 64 + lane];
#pragma unroll
  for (int sq = 0; sq < 2; ++sq) {
    const float* src = qkv + (size_t)n * 6144 + sq * 2048 + h * 128;
    float2 v = reinterpret_cast<const float2*>(src)[lane];
    float ss = v.x * v.x + v.y * v.y;
#pragma unroll
    for (int m = 1; m < 64; m <<= 1) ss += __shfl_xor(ss, m, 64);
    const float r = rsqrtf(ss * (1.0f / 128.0f) + 1e-6f);
    float2 wv = reinterpret_cast<const float2*>(sq == 0 ? qw : kw)[lane];
    const float xr = v.x * r * wv.x;
    const float xi = v.y * r * wv.y;
    float orr = xr * c - xi * s;
    float oi  = xr * s + xi * c;
    if (sq == 0) { orr *= 0.08838834764831845f; oi *= 0.08838834764831845f; }
    unsigned short* dst = (sq == 0 ? qo : ko) + ((size_t)h * 2048 + n) * 128 + 2 * lane;
    const unsigned int pk = (unsigned int)f2bf(orr) | ((unsigned int)f2bf(oi) << 16);
    *reinterpret_cast<unsigned int*>(dst) = pk;
  }
}

// ============ 4b. v transpose: fp32 -> vt[h][d][n] bf16 ============
__global__ __launch_bounds__(256) void k_v_tr(const float* __restrict__ qkv,
                                              unsigned short* __restrict__ vt) {
  __shared__ __align__(16) unsigned short tile[64][130];
  const int h = blockIdx.y;
  const int n0 = blockIdx.x * 64;
  const int t = threadIdx.x;
  {
    const int row = t >> 2;
    const int c0 = (t & 3) * 32;
    const float* src = qkv + (size_t)(n0 + row) * 6144 + 4096 + h * 128 + c0;
#pragma unroll
    for (int j = 0; j < 32; j += 4) {
      float4 v = reinterpret_cast<const float4*>(src + j)[0];
      tile[row][c0 + j + 0] = f2bf(v.x);
      tile[row][c0 + j + 1] = f2bf(v.y);
      tile[row][c0 + j + 2] = f2bf(v.z);
      tile[row][c0 + j + 3] = f2bf(v.w);
    }
  }
  __syncthreads();
  {
    const int d = t >> 1;
    const int nc = (t & 1) * 32;
    unsigned short* dst = vt + ((size_t)h * 128 + d) * 2048 + n0 + nc;
#pragma unroll
    for (int j = 0; j < 32; j += 8) {
      bf16x8 o;
#pragma unroll
      for (int jj = 0; jj < 8; ++jj) o[jj] = (short)tile[nc + j + jj][d];
      *reinterpret_cast<bf16x8*>(dst + j) = o;
    }
  }
}

// ============ 5. flash attention v2: swapped QK^T (S^T), in-lane softmax,
// double-buffered K/V staging, setprio MFMA clusters, defer-max rescale.
__global__ __launch_bounds__(256) void k_fattn(const unsigned short* __restrict__ q,
                                               const unsigned short* __restrict__ k,
                                               const unsigned short* __restrict__ vt,
                                               unsigned short* __restrict__ out) {
  __shared__ __align__(16) unsigned short Ks[2][64 * 128];
  __shared__ __align__(16) unsigned short Vs[2][128 * 64];
  __shared__ __align__(16) unsigned short Ps[4][16][72];
  const int lane = threadIdx.x & 63;
  const int wid = threadIdx.x >> 6;
  const int h = blockIdx.x & 15;
  const int qb = blockIdx.x >> 4;
  const int q0 = qb * 64 + wid * 16;

  // Stage one 64-key K tile + Vt tile into buf (pre-swizzled global source,
  // linear LDS dest — m173 pattern; physical col = logical col ^ ((row&7)<<4)).
  auto stage = [&](int buf, int kt) {
#pragma unroll
    for (int i = 0; i < 4; ++i) {
      const int c = i * 4 + wid;
      const int off = c * 1024 + lane * 16;
      const int krow = off >> 8;
      const int kcb = (off & 255) ^ ((krow & 7) << 4);
      gload_lds16(k + ((size_t)h * 2048 + kt * 64 + krow) * 128 + (kcb >> 1),
                  (char*)Ks[buf] + c * 1024);
      const int vrow = off >> 7;
      const int vcb = (off & 127) ^ ((vrow & 7) << 4);
      gload_lds16(vt + ((size_t)h * 128 + vrow) * 2048 + kt * 64 + (vcb >> 1),
                  (char*)Vs[buf] + c * 1024);
    }
  };

  bf16x8 qf[4];
  {
    const unsigned short* qp = q + ((size_t)h * 2048 + q0 + (lane & 15)) * 128 + (lane >> 4) * 8;
#pragma unroll
    for (int kc = 0; kc < 4; ++kc) qf[kc] = *reinterpret_cast<const bf16x8*>(qp + kc * 32);
  }
  f32x4 O[8];
#pragma unroll
  for (int i = 0; i < 8; ++i) O[i] = (f32x4){0.f, 0.f, 0.f, 0.f};
  float m = -1e30f, l = 0.f;   // per-lane: q-row = q0 + (lane&15)

  stage(0, 0);
  __syncthreads();

  for (int kt = 0; kt < 32; ++kt) {
    const int cur = kt & 1;
    if (kt < 31) stage(cur ^ 1, kt + 1);   // prefetch under this tile's compute

    // S^T[key][q] = K·Q^T : A = K rows (key), B = Q^T cols (q).
    f32x4 sf[4];
    __builtin_amdgcn_s_setprio(1);
#pragma unroll
    for (int ni = 0; ni < 4; ++ni) {
      f32x4 a = (f32x4){0.f, 0.f, 0.f, 0.f};
      const int key = ni * 16 + (lane & 15);
#pragma unroll
      for (int kc = 0; kc < 4; ++kc) {
        const int db = (kc * 64 + (lane >> 4) * 16) ^ ((key & 7) << 4);
        bf16x8 af = *reinterpret_cast<const bf16x8*>((const char*)Ks[cur] + key * 256 + db);
        a = __builtin_amdgcn_mfma_f32_16x16x32_bf16(af, qf[kc], a, 0, 0, 0);
      }
      sf[ni] = a;
    }
    __builtin_amdgcn_s_setprio(0);
    // lane holds S^T[k = ni*16 + (lane>>4)*4 + j][q = lane&15] : 16 keys of ONE q-row.

    // --- in-lane online softmax ---
    float mt = fmaxf(fmaxf(sf[0][0], sf[0][1]), fmaxf(sf[0][2], sf[0][3]));
#pragma unroll
    for (int ni = 1; ni < 4; ++ni)
      mt = fmaxf(mt, fmaxf(fmaxf(sf[ni][0], sf[ni][1]), fmaxf(sf[ni][2], sf[ni][3])));
    mt = fmaxf(mt, __shfl_xor(mt, 16, 64));
    mt = fmaxf(mt, __shfl_xor(mt, 32, 64));

    if (!__all(mt <= m + 8.0f)) {          // defer-max (T13, THR=8)
      const float mn = fmaxf(m, mt);
      const float al = __expf(m - mn);
      m = mn;
      l *= al;
#pragma unroll
      for (int dc = 0; dc < 8; ++dc)
#pragma unroll
        for (int j = 0; j < 4; ++j) O[dc][j] *= al;
    }
    float rs = 0.f;
#pragma unroll
    for (int ni = 0; ni < 4; ++ni)
#pragma unroll
      for (int j = 0; j < 4; ++j) {
        const float p = __expf(sf[ni][j] - m);
        sf[ni][j] = p;
        rs += p;
      }
    rs += __shfl_xor(rs, 16, 64);
    rs += __shfl_xor(rs, 32, 64);
    l += rs;

    // P^T -> Ps[wid][q][k] (packed 8B writes), then B-operand frags (16B reads)
#pragma unroll
    for (int ni = 0; ni < 4; ++ni) {
      ushort4 pk;
      pk.x = f2bf(sf[ni][0]); pk.y = f2bf(sf[ni][1]);
      pk.z = f2bf(sf[ni][2]); pk.w = f2bf(sf[ni][3]);
      *reinterpret_cast<ushort4*>(&Ps[wid][lane & 15][ni * 16 + (lane >> 4) * 4]) = pk;
    }
    bf16x8 pa[2];
#pragma unroll
    for (int ks = 0; ks < 2; ++ks)
      pa[ks] = *reinterpret_cast<const bf16x8*>(&Ps[wid][lane & 15][ks * 32 + (lane >> 4) * 8]);

    // O^T[d][q] += Vt·P^T : A = Vt rows (d), B = P^T cols (q).
    __builtin_amdgcn_s_setprio(1);
#pragma unroll
    for (int dc = 0; dc < 8; ++dc) {
      const int d = dc * 16 + (lane & 15);
#pragma unroll
      for (int ks = 0; ks < 2; ++ks) {
        const int kb = (ks * 64 + (lane >> 4) * 16) ^ ((d & 7) << 4);
        bf16x8 af = *reinterpret_cast<const bf16x8*>((const char*)Vs[cur] + d * 128 + kb);
        O[dc] = __builtin_amdgcn_mfma_f32_16x16x32_bf16(af, pa[ks], O[dc], 0, 0, 0);
      }
    }
    __builtin_amdgcn_s_setprio(0);
    __syncthreads();   // drains prefetch vmcnt + protects buffer reuse
  }

  const float rl = 1.0f / l;
  const int qrow = q0 + (lane & 15);
#pragma unroll
  for (int dc = 0; dc < 8; ++dc) {
    ushort4 o;
    o.x = f2bf(O[dc][0] * rl); o.y = f2bf(O[dc][1] * rl);
    o.z = f2bf(O[dc][2] * rl); o.w = f2bf(O[dc][3] * rl);
    *reinterpret_cast<ushort4*>(
        &out[(size_t)qrow * 2048 + h * 128 + dc * 16 + (lane >> 4) * 4]) = o;
  }
}

extern "C" void kernel_launch(void* const* d_in, const int* in_sizes, int n_in,
                              void* d_out, int out_size, void* d_ws, size_t ws_size,
                              hipStream_t stream) {
  (void)in_sizes; (void)n_in; (void)out_size; (void)ws_size;
  const float* x      = (const float*)d_in[0];
  const float* qkv_w  = (const float*)d_in[1];
  const float* qkv_b  = (const float*)d_in[2];
  const float* proj_w = (const float*)d_in[3];
  const float* proj_b = (const float*)d_in[4];
  const float* q_nw   = (const float*)d_in[5];
  const float* k_nw   = (const float*)d_in[6];
  const int* h_dim    = (const int*)d_in[8];
  const int* w_dim    = (const int*)d_in[9];
  float* out = (float*)d_out;

  char* ws = (char*)d_ws;
  size_t off = 0;
  auto carve = [&](size_t bytes) -> void* {
    void* p = ws + off;
    off += (bytes + 255) & ~(size_t)255;
    return p;
  };
  unsigned short* x_bf   = (unsigned short*)carve(2048ull * 2048 * 2);
  unsigned short* w1_bf  = (unsigned short*)carve(6144ull * 2048 * 2);
  unsigned short* w2_bf  = (unsigned short*)carve(2048ull * 2048 * 2);
  float*          qkvf   = (float*)carve(2048ull * 6144 * 4);
  unsigned short* q_bf   = (unsigned short*)carve(16ull * 2048 * 128 * 2);
  unsigned short* k_bf   = (unsigned short*)carve(16ull * 2048 * 128 * 2);
  unsigned short* vt_bf  = (unsigned short*)carve(16ull * 2048 * 128 * 2);
  unsigned short* att_bf = (unsigned short*)carve(2048ull * 2048 * 2);
  float*          cosT   = (float*)carve(2048ull * 64 * 4);
  float*          sinT   = (float*)carve(2048ull * 64 * 4);

  hipLaunchKernelGGL(k_cvt_bf16, dim3(2048), dim3(256), 0, stream, x, x_bf, 2048 * 2048 / 4);
  hipLaunchKernelGGL(k_cvt_bf16, dim3(2048), dim3(256), 0, stream, qkv_w, w1_bf, 6144 * 2048 / 4);
  hipLaunchKernelGGL(k_cvt_bf16, dim3(2048), dim3(256), 0, stream, proj_w, w2_bf, 2048 * 2048 / 4);
  hipLaunchKernelGGL(k_rope_tab, dim3(512), dim3(256), 0, stream, cosT, sinT, h_dim, w_dim);
  hipLaunchKernelGGL(k_gemm_bt, dim3(48, 16), dim3(256), 0, stream,
                     x_bf, w1_bf, qkv_b, qkvf, 2048, 6144, 2048);
  hipLaunchKernelGGL(k_qk_post, dim3(8192), dim3(256), 0, stream,
                     qkvf, q_nw, k_nw, cosT, sinT, q_bf, k_bf);
  hipLaunchKernelGGL(k_v_tr, dim3(32, 16), dim3(256), 0, stream, qkvf, vt_bf);
  hipLaunchKernelGGL(k_fattn, dim3(512), dim3(256), 0, stream, q_bf, k_bf, vt_bf, att_bf);
  hipLaunchKernelGGL(k_gemm_bt, dim3(16, 16), dim3(256), 0, stream,
                     att_bf, w2_bf, proj_b, out, 2048, 2048, 2048);
}

// Round 3
// 213.934 us; speedup vs baseline: 1.1682x; 1.0126x over previous
//
#include <hip/hip_runtime.h>
#include <hip/hip_bf16.h>
#include <cstdint>
#include <cstddef>

typedef __attribute__((ext_vector_type(8))) short bf16x8;
typedef __attribute__((ext_vector_type(4))) float f32x4;

#define AS1 __attribute__((address_space(1)))
#define AS3 __attribute__((address_space(3)))

__device__ __forceinline__ void gload_lds16(const void* g, void* l) {
  __builtin_amdgcn_global_load_lds((const AS1 void*)g, (AS3 void*)l, 16, 0, 0);
}

__device__ __forceinline__ unsigned short f2bf(float x) {
  __hip_bfloat16 h = __float2bfloat16(x);
  return __builtin_bit_cast(unsigned short, h);
}

// ============ 1. f32 -> bf16 convert ============
__global__ __launch_bounds__(256) void k_cvt_bf16(const float* __restrict__ in,
                                                  unsigned short* __restrict__ out,
                                                  int n4) {
  int i = blockIdx.x * 256 + threadIdx.x;
  const int stride = gridDim.x * 256;
  for (; i < n4; i += stride) {
    float4 v = reinterpret_cast<const float4*>(in)[i];
    ushort4 o;
    o.x = f2bf(v.x); o.y = f2bf(v.y); o.z = f2bf(v.z); o.w = f2bf(v.w);
    reinterpret_cast<ushort4*>(out)[i] = o;
  }
}

// ============ 2. RoPE cos/sin tables [2048][64] ============
__global__ __launch_bounds__(256) void k_rope_tab(float* __restrict__ cosT,
                                                  float* __restrict__ sinT,
                                                  const int* __restrict__ hdim,
                                                  const int* __restrict__ wdim) {
  int idx = blockIdx.x * 256 + threadIdx.x;
  if (idx >= 2048 * 64) return;
  const int n = idx >> 6, j = idx & 63;
  const int H = *hdim, W = *wdim;
  const int w = n % W;
  const int rem = n / W;
  const int h = rem % H;
  const int t = rem / H;
  float pos, i2, d;
  if (j < 22)      { pos = (float)t; i2 = (float)(2 * j);        d = 44.f; }
  else if (j < 43) { pos = (float)h; i2 = (float)(2 * (j - 22)); d = 42.f; }
  else             { pos = (float)w; i2 = (float)(2 * (j - 43)); d = 42.f; }
  const float ang = pos * powf(10000.0f, -i2 / d);
  cosT[idx] = cosf(ang);
  sinT[idx] = sinf(ang);
}

// ============ 3a. 256x256 8-wave counted-vmcnt GEMM (T3+T4+T2+T5) ============
// C[M][N] = A[M][K]*B[N][K]^T + bias. BK=32, ring-4 LDS (4 x (16KB A + 16KB B)).
// Requires M%256==0, N%256==0, K%32==0, K/32>=4, grid%8==0.
__global__ __launch_bounds__(512, 2) void k_gemm256(const unsigned short* __restrict__ A,
                                                    const unsigned short* __restrict__ B,
                                                    const float* __restrict__ bias,
                                                    float* __restrict__ C,
                                                    int M, int N, int K) {
  __shared__ __align__(16) char lds[131072];
  const int tid = threadIdx.x;
  const int lane = tid & 63;
  const int wid = tid >> 6;
  const int wr = wid >> 2, wc = wid & 3;

  const int nbx = N >> 8;
  const int cpx = gridDim.x >> 3;                     // blocks per XCD
  const int swz = (blockIdx.x & 7) * cpx + (blockIdx.x >> 3);
  const int by = swz / nbx, bx = swz % nbx;
  const int row0 = by * 256, col0 = bx * 256;
  const int NT = K >> 5;

  // Stage 8KB round r of a 16KB [256][32bf16] region. Dest is linear
  // (wave-uniform base + lane*16); source pre-swizzled: pcol = lcol ^ ((row&3)<<4).
  auto stage_round = [&](const unsigned short* src, int grow0, int kt, char* region, int r) {
    const int off = r * 8192 + tid * 16;
    const int row = off >> 6;
    const int lcolb = (off & 63) ^ ((row & 3) << 4);
    gload_lds16(src + (size_t)(grow0 + row) * K + kt * 32 + (lcolb >> 1),
                region + r * 8192 + wid * 1024);
  };

  f32x4 acc[8][4];
#pragma unroll
  for (int i = 0; i < 8; ++i)
#pragma unroll
    for (int j = 0; j < 4; ++j) acc[i][j] = (f32x4){0.f, 0.f, 0.f, 0.f};

  // Prologue: stage tiles 0,1,2 (12 loads/thread); vmcnt(8) completes tile 0.
  for (int t = 0; t < 3; ++t) {
    char* Ar = lds + (t & 3) * 32768;
    stage_round(A, row0, t, Ar, 0);
    stage_round(A, row0, t, Ar, 1);
    stage_round(B, col0, t, Ar + 16384, 0);
    stage_round(B, col0, t, Ar + 16384, 1);
  }
  asm volatile("s_waitcnt vmcnt(8)" ::: "memory");
  __builtin_amdgcn_s_barrier();

  for (int j = 0; j < NT; ++j) {
    const char* Ab = lds + (j & 3) * 32768;
    const char* Bb = Ab + 16384;
    const int jp = j + 3;
    char* Sr = lds + (jp & 3) * 32768;
    // ---- phase A: stage A(j+3), read B-frags + A rows 0-3, 16 MFMA ----
    if (jp < NT) { stage_round(A, row0, jp, Sr, 0); stage_round(A, row0, jp, Sr, 1); }
    bf16x8 bfr[4], af[4];
#pragma unroll
    for (int fc = 0; fc < 4; ++fc) {
      const int rb = wc * 64 + fc * 16 + (lane & 15);
      bfr[fc] = *reinterpret_cast<const bf16x8*>(
          Bb + rb * 64 + (((lane >> 4) * 16) ^ ((rb & 3) << 4)));
    }
#pragma unroll
    for (int fr = 0; fr < 4; ++fr) {
      const int ra = wr * 128 + fr * 16 + (lane & 15);
      af[fr] = *reinterpret_cast<const bf16x8*>(
          Ab + ra * 64 + (((lane >> 4) * 16) ^ ((ra & 3) << 4)));
    }
    __builtin_amdgcn_s_setprio(1);
#pragma unroll
    for (int fr = 0; fr < 4; ++fr)
#pragma unroll
      for (int fc = 0; fc < 4; ++fc)
        acc[fr][fc] = __builtin_amdgcn_mfma_f32_16x16x32_bf16(af[fr], bfr[fc], acc[fr][fc], 0, 0, 0);
    __builtin_amdgcn_s_setprio(0);
    __builtin_amdgcn_s_barrier();
    // ---- phase B: stage B(j+3), read A rows 4-7, 16 MFMA ----
    if (jp < NT) { stage_round(B, col0, jp, Sr + 16384, 0); stage_round(B, col0, jp, Sr + 16384, 1); }
#pragma unroll
    for (int fr = 0; fr < 4; ++fr) {
      const int ra = wr * 128 + (fr + 4) * 16 + (lane & 15);
      af[fr] = *reinterpret_cast<const bf16x8*>(
          Ab + ra * 64 + (((lane >> 4) * 16) ^ ((ra & 3) << 4)));
    }
    __builtin_amdgcn_s_setprio(1);
#pragma unroll
    for (int fr = 0; fr < 4; ++fr)
#pragma unroll
      for (int fc = 0; fc < 4; ++fc)
        acc[fr + 4][fc] = __builtin_amdgcn_mfma_f32_16x16x32_bf16(af[fr], bfr[fc], acc[fr + 4][fc], 0, 0, 0);
    __builtin_amdgcn_s_setprio(0);
    // counted wait: keep 2 tiles in flight; drain 8 -> 4 -> 0 at the tail.
    if (j + 3 < NT)      asm volatile("s_waitcnt vmcnt(8)" ::: "memory");
    else if (j + 2 < NT) asm volatile("s_waitcnt vmcnt(4)" ::: "memory");
    else if (j + 1 < NT) asm volatile("s_waitcnt vmcnt(0)" ::: "memory");
    __builtin_amdgcn_s_barrier();
  }

#pragma unroll
  for (int fr = 0; fr < 8; ++fr)
#pragma unroll
    for (int fc = 0; fc < 4; ++fc) {
      const int col = col0 + wc * 64 + fc * 16 + (lane & 15);
      const float bv = bias[col];
#pragma unroll
      for (int jj = 0; jj < 4; ++jj) {
        const int row = row0 + wr * 128 + fr * 16 + (lane >> 4) * 4 + jj;
        C[(size_t)row * N + col] = acc[fr][fc][jj] + bv;
      }
    }
}

// ============ 3b. 128x128 m97-structure GEMM (kept for proj: 256 blocks) ====
__global__ __launch_bounds__(256) void k_gemm_bt(const unsigned short* __restrict__ A,
                                                 const unsigned short* __restrict__ B,
                                                 const float* __restrict__ bias,
                                                 float* __restrict__ C,
                                                 int M, int N, int K) {
  __shared__ __align__(16) unsigned short As[128 * 32];
  __shared__ __align__(16) unsigned short Bs[128 * 32];
  const int lane = threadIdx.x & 63;
  const int wid  = threadIdx.x >> 6;
  const int wr = wid >> 1, wc = wid & 1;
  const int rowA0 = blockIdx.y * 128;
  const int rowB0 = blockIdx.x * 128;

  f32x4 acc[4][4];
#pragma unroll
  for (int i = 0; i < 4; ++i)
#pragma unroll
    for (int j = 0; j < 4; ++j) acc[i][j] = (f32x4){0.f, 0.f, 0.f, 0.f};

  for (int kt = 0; kt < K; kt += 32) {
#pragma unroll
    for (int i = 0; i < 2; ++i) {
      const int c = i * 4 + wid;
      const int off = c * 1024 + lane * 16;
      const int row = off >> 6;
      const int col = (off & 63) >> 1;
      gload_lds16(A + (size_t)(rowA0 + row) * K + kt + col, (char*)As + c * 1024);
      gload_lds16(B + (size_t)(rowB0 + row) * K + kt + col, (char*)Bs + c * 1024);
    }
    __syncthreads();
    bf16x8 af[4], bfr[4];
#pragma unroll
    for (int mi = 0; mi < 4; ++mi)
      af[mi] = *reinterpret_cast<const bf16x8*>(
          &As[(wr * 64 + mi * 16 + (lane & 15)) * 32 + (lane >> 4) * 8]);
#pragma unroll
    for (int ni = 0; ni < 4; ++ni)
      bfr[ni] = *reinterpret_cast<const bf16x8*>(
          &Bs[(wc * 64 + ni * 16 + (lane & 15)) * 32 + (lane >> 4) * 8]);
#pragma unroll
    for (int mi = 0; mi < 4; ++mi)
#pragma unroll
      for (int ni = 0; ni < 4; ++ni)
        acc[mi][ni] = __builtin_amdgcn_mfma_f32_16x16x32_bf16(af[mi], bfr[ni], acc[mi][ni], 0, 0, 0);
    __syncthreads();
  }

#pragma unroll
  for (int mi = 0; mi < 4; ++mi)
#pragma unroll
    for (int ni = 0; ni < 4; ++ni) {
      const int col = rowB0 + wc * 64 + ni * 16 + (lane & 15);
      const float b = bias[col];
#pragma unroll
      for (int j = 0; j < 4; ++j) {
        const int row = rowA0 + wr * 64 + mi * 16 + (lane >> 4) * 4 + j;
        C[(size_t)row * N + col] = acc[mi][ni][j] + b;
      }
    }
}

// ============ 4a. q/k: RMSNorm + RoPE + (q: fold softmax scale) -> bf16 [h][n][d]
__global__ __launch_bounds__(256) void k_qk_post(const float* __restrict__ qkv,
                                                 const float* __restrict__ qw,
                                                 const float* __restrict__ kw,
                                                 const float* __restrict__ cosT,
                                                 const float* __restrict__ sinT,
                                                 unsigned short* __restrict__ qo,
                                                 unsigned short* __restrict__ ko) {
  const int lane = threadIdx.x & 63;
  const int wid = threadIdx.x >> 6;
  const int pair = blockIdx.x * 4 + wid;  // (n,h)
  const int n = pair >> 4, h = pair & 15;
  const float c = cosT[n * 64 + lane];
  const float s = sinT[n * 64 + lane];
#pragma unroll
  for (int sq = 0; sq < 2; ++sq) {
    const float* src = qkv + (size_t)n * 6144 + sq * 2048 + h * 128;
    float2 v = reinterpret_cast<const float2*>(src)[lane];
    float ss = v.x * v.x + v.y * v.y;
#pragma unroll
    for (int m = 1; m < 64; m <<= 1) ss += __shfl_xor(ss, m, 64);
    const float r = rsqrtf(ss * (1.0f / 128.0f) + 1e-6f);
    float2 wv = reinterpret_cast<const float2*>(sq == 0 ? qw : kw)[lane];
    const float xr = v.x * r * wv.x;
    const float xi = v.y * r * wv.y;
    float orr = xr * c - xi * s;
    float oi  = xr * s + xi * c;
    if (sq == 0) { orr *= 0.08838834764831845f; oi *= 0.08838834764831845f; }
    unsigned short* dst = (sq == 0 ? qo : ko) + ((size_t)h * 2048 + n) * 128 + 2 * lane;
    const unsigned int pk = (unsigned int)f2bf(orr) | ((unsigned int)f2bf(oi) << 16);
    *reinterpret_cast<unsigned int*>(dst) = pk;
  }
}

// ============ 4b. v transpose: fp32 -> vt[h][d][n] bf16 ============
__global__ __launch_bounds__(256) void k_v_tr(const float* __restrict__ qkv,
                                              unsigned short* __restrict__ vt) {
  __shared__ __align__(16) unsigned short tile[64][130];
  const int h = blockIdx.y;
  const int n0 = blockIdx.x * 64;
  const int t = threadIdx.x;
  {
    const int row = t >> 2;
    const int c0 = (t & 3) * 32;
    const float* src = qkv + (size_t)(n0 + row) * 6144 + 4096 + h * 128 + c0;
#pragma unroll
    for (int j = 0; j < 32; j += 4) {
      float4 v = reinterpret_cast<const float4*>(src + j)[0];
      tile[row][c0 + j + 0] = f2bf(v.x);
      tile[row][c0 + j + 1] = f2bf(v.y);
      tile[row][c0 + j + 2] = f2bf(v.z);
      tile[row][c0 + j + 3] = f2bf(v.w);
    }
  }
  __syncthreads();
  {
    const int d = t >> 1;
    const int nc = (t & 1) * 32;
    unsigned short* dst = vt + ((size_t)h * 128 + d) * 2048 + n0 + nc;
#pragma unroll
    for (int j = 0; j < 32; j += 8) {
      bf16x8 o;
#pragma unroll
      for (int jj = 0; jj < 8; ++jj) o[jj] = (short)tile[nc + j + jj][d];
      *reinterpret_cast<bf16x8*>(dst + j) = o;
    }
  }
}

// ============ 5. flash attention (swapped QK^T, in-lane softmax, dbuf staging)
__global__ __launch_bounds__(256) void k_fattn(const unsigned short* __restrict__ q,
                                               const unsigned short* __restrict__ k,
                                               const unsigned short* __restrict__ vt,
                                               unsigned short* __restrict__ out) {
  __shared__ __align__(16) unsigned short Ks[2][64 * 128];
  __shared__ __align__(16) unsigned short Vs[2][128 * 64];
  __shared__ __align__(16) unsigned short Ps[4][16][72];
  const int lane = threadIdx.x & 63;
  const int wid = threadIdx.x >> 6;
  const int h = blockIdx.x & 15;
  const int qb = blockIdx.x >> 4;
  const int q0 = qb * 64 + wid * 16;

  auto stage = [&](int buf, int kt) {
#pragma unroll
    for (int i = 0; i < 4; ++i) {
      const int c = i * 4 + wid;
      const int off = c * 1024 + lane * 16;
      const int krow = off >> 8;
      const int kcb = (off & 255) ^ ((krow & 7) << 4);
      gload_lds16(k + ((size_t)h * 2048 + kt * 64 + krow) * 128 + (kcb >> 1),
                  (char*)Ks[buf] + c * 1024);
      const int vrow = off >> 7;
      const int vcb = (off & 127) ^ ((vrow & 7) << 4);
      gload_lds16(vt + ((size_t)h * 128 + vrow) * 2048 + kt * 64 + (vcb >> 1),
                  (char*)Vs[buf] + c * 1024);
    }
  };

  bf16x8 qf[4];
  {
    const unsigned short* qp = q + ((size_t)h * 2048 + q0 + (lane & 15)) * 128 + (lane >> 4) * 8;
#pragma unroll
    for (int kc = 0; kc < 4; ++kc) qf[kc] = *reinterpret_cast<const bf16x8*>(qp + kc * 32);
  }
  f32x4 O[8];
#pragma unroll
  for (int i = 0; i < 8; ++i) O[i] = (f32x4){0.f, 0.f, 0.f, 0.f};
  float m = -1e30f, l = 0.f;

  stage(0, 0);
  __syncthreads();

  for (int kt = 0; kt < 32; ++kt) {
    const int cur = kt & 1;
    if (kt < 31) stage(cur ^ 1, kt + 1);

    f32x4 sf[4];
    __builtin_amdgcn_s_setprio(1);
#pragma unroll
    for (int ni = 0; ni < 4; ++ni) {
      f32x4 a = (f32x4){0.f, 0.f, 0.f, 0.f};
      const int key = ni * 16 + (lane & 15);
#pragma unroll
      for (int kc = 0; kc < 4; ++kc) {
        const int db = (kc * 64 + (lane >> 4) * 16) ^ ((key & 7) << 4);
        bf16x8 af = *reinterpret_cast<const bf16x8*>((const char*)Ks[cur] + key * 256 + db);
        a = __builtin_amdgcn_mfma_f32_16x16x32_bf16(af, qf[kc], a, 0, 0, 0);
      }
      sf[ni] = a;
    }
    __builtin_amdgcn_s_setprio(0);

    float mt = fmaxf(fmaxf(sf[0][0], sf[0][1]), fmaxf(sf[0][2], sf[0][3]));
#pragma unroll
    for (int ni = 1; ni < 4; ++ni)
      mt = fmaxf(mt, fmaxf(fmaxf(sf[ni][0], sf[ni][1]), fmaxf(sf[ni][2], sf[ni][3])));
    mt = fmaxf(mt, __shfl_xor(mt, 16, 64));
    mt = fmaxf(mt, __shfl_xor(mt, 32, 64));

    if (!__all(mt <= m + 8.0f)) {
      const float mn = fmaxf(m, mt);
      const float al = __expf(m - mn);
      m = mn;
      l *= al;
#pragma unroll
      for (int dc = 0; dc < 8; ++dc)
#pragma unroll
        for (int j = 0; j < 4; ++j) O[dc][j] *= al;
    }
    float rs = 0.f;
#pragma unroll
    for (int ni = 0; ni < 4; ++ni)
#pragma unroll
      for (int j = 0; j < 4; ++j) {
        const float p = __expf(sf[ni][j] - m);
        sf[ni][j] = p;
        rs += p;
      }
    rs += __shfl_xor(rs, 16, 64);
    rs += __shfl_xor(rs, 32, 64);
    l += rs;

#pragma unroll
    for (int ni = 0; ni < 4; ++ni) {
      ushort4 pk;
      pk.x = f2bf(sf[ni][0]); pk.y = f2bf(sf[ni][1]);
      pk.z = f2bf(sf[ni][2]); pk.w = f2bf(sf[ni][3]);
      *reinterpret_cast<ushort4*>(&Ps[wid][lane & 15][ni * 16 + (lane >> 4) * 4]) = pk;
    }
    bf16x8 pa[2];
#pragma unroll
    for (int ks = 0; ks < 2; ++ks)
      pa[ks] = *reinterpret_cast<const bf16x8*>(&Ps[wid][lane & 15][ks * 32 + (lane >> 4) * 8]);

    __builtin_amdgcn_s_setprio(1);
#pragma unroll
    for (int dc = 0; dc < 8; ++dc) {
      const int d = dc * 16 + (lane & 15);
#pragma unroll
      for (int ks = 0; ks < 2; ++ks) {
        const int kb = (ks * 64 + (lane >> 4) * 16) ^ ((d & 7) << 4);
        bf16x8 af = *reinterpret_cast<const bf16x8*>((const char*)Vs[cur] + d * 128 + kb);
        O[dc] = __builtin_amdgcn_mfma_f32_16x16x32_bf16(af, pa[ks], O[dc], 0, 0, 0);
      }
    }
    __builtin_amdgcn_s_setprio(0);
    __syncthreads();
  }

  const float rl = 1.0f / l;
  const int qrow = q0 + (lane & 15);
#pragma unroll
  for (int dc = 0; dc < 8; ++dc) {
    ushort4 o;
    o.x = f2bf(O[dc][0] * rl); o.y = f2bf(O[dc][1] * rl);
    o.z = f2bf(O[dc][2] * rl); o.w = f2bf(O[dc][3] * rl);
    *reinterpret_cast<ushort4*>(
        &out[(size_t)qrow * 2048 + h * 128 + dc * 16 + (lane >> 4) * 4]) = o;
  }
}

extern "C" void kernel_launch(void* const* d_in, const int* in_sizes, int n_in,
                              void* d_out, int out_size, void* d_ws, size_t ws_size,
                              hipStream_t stream) {
  (void)in_sizes; (void)n_in; (void)out_size; (void)ws_size;
  const float* x      = (const float*)d_in[0];
  const float* qkv_w  = (const float*)d_in[1];
  const float* qkv_b  = (const float*)d_in[2];
  const float* proj_w = (const float*)d_in[3];
  const float* proj_b = (const float*)d_in[4];
  const float* q_nw   = (const float*)d_in[5];
  const float* k_nw   = (const float*)d_in[6];
  const int* h_dim    = (const int*)d_in[8];
  const int* w_dim    = (const int*)d_in[9];
  float* out = (float*)d_out;

  char* ws = (char*)d_ws;
  size_t off = 0;
  auto carve = [&](size_t bytes) -> void* {
    void* p = ws + off;
    off += (bytes + 255) & ~(size_t)255;
    return p;
  };
  unsigned short* x_bf   = (unsigned short*)carve(2048ull * 2048 * 2);
  unsigned short* w1_bf  = (unsigned short*)carve(6144ull * 2048 * 2);
  unsigned short* w2_bf  = (unsigned short*)carve(2048ull * 2048 * 2);
  float*          qkvf   = (float*)carve(2048ull * 6144 * 4);
  unsigned short* q_bf   = (unsigned short*)carve(16ull * 2048 * 128 * 2);
  unsigned short* k_bf   = (unsigned short*)carve(16ull * 2048 * 128 * 2);
  unsigned short* vt_bf  = (unsigned short*)carve(16ull * 2048 * 128 * 2);
  unsigned short* att_bf = (unsigned short*)carve(2048ull * 2048 * 2);
  float*          cosT   = (float*)carve(2048ull * 64 * 4);
  float*          sinT   = (float*)carve(2048ull * 64 * 4);

  hipLaunchKernelGGL(k_cvt_bf16, dim3(2048), dim3(256), 0, stream, x, x_bf, 2048 * 2048 / 4);
  hipLaunchKernelGGL(k_cvt_bf16, dim3(2048), dim3(256), 0, stream, qkv_w, w1_bf, 6144 * 2048 / 4);
  hipLaunchKernelGGL(k_cvt_bf16, dim3(2048), dim3(256), 0, stream, proj_w, w2_bf, 2048 * 2048 / 4);
  hipLaunchKernelGGL(k_rope_tab, dim3(512), dim3(256), 0, stream, cosT, sinT, h_dim, w_dim);
  // QKV: M=2048, N=6144 -> 8x24 = 192 blocks of 512 threads (256^2 tiles)
  hipLaunchKernelGGL(k_gemm256, dim3(192), dim3(512), 0, stream,
                     x_bf, w1_bf, qkv_b, qkvf, 2048, 6144, 2048);
  hipLaunchKernelGGL(k_qk_post, dim3(8192), dim3(256), 0, stream,
                     qkvf, q_nw, k_nw, cosT, sinT, q_bf, k_bf);
  hipLaunchKernelGGL(k_v_tr, dim3(32, 16), dim3(256), 0, stream, qkvf, vt_bf);
  hipLaunchKernelGGL(k_fattn, dim3(512), dim3(256), 0, stream, q_bf, k_bf, vt_bf, att_bf);
  hipLaunchKernelGGL(k_gemm_bt, dim3(16, 16), dim3(256), 0, stream,
                     att_bf, w2_bf, proj_b, out, 2048, 2048, 2048);
}

// Round 4
// 207.640 us; speedup vs baseline: 1.2036x; 1.0303x over previous
//
#include <hip/hip_runtime.h>
#include <hip/hip_bf16.h>
#include <cstdint>
#include <cstddef>

typedef __attribute__((ext_vector_type(8))) short bf16x8;
typedef __attribute__((ext_vector_type(4))) float f32x4;

#define AS1 __attribute__((address_space(1)))
#define AS3 __attribute__((address_space(3)))

__device__ __forceinline__ void gload_lds16(const void* g, void* l) {
  __builtin_amdgcn_global_load_lds((const AS1 void*)g, (AS3 void*)l, 16, 0, 0);
}

__device__ __forceinline__ unsigned short f2bf(float x) {
  __hip_bfloat16 h = __float2bfloat16(x);
  return __builtin_bit_cast(unsigned short, h);
}

// ============ 1. f32 -> bf16 convert ============
__global__ __launch_bounds__(256) void k_cvt_bf16(const float* __restrict__ in,
                                                  unsigned short* __restrict__ out,
                                                  int n4) {
  int i = blockIdx.x * 256 + threadIdx.x;
  const int stride = gridDim.x * 256;
  for (; i < n4; i += stride) {
    float4 v = reinterpret_cast<const float4*>(in)[i];
    ushort4 o;
    o.x = f2bf(v.x); o.y = f2bf(v.y); o.z = f2bf(v.z); o.w = f2bf(v.w);
    reinterpret_cast<ushort4*>(out)[i] = o;
  }
}

// ============ 2. RoPE cos/sin tables [2048][64] ============
__global__ __launch_bounds__(256) void k_rope_tab(float* __restrict__ cosT,
                                                  float* __restrict__ sinT,
                                                  const int* __restrict__ hdim,
                                                  const int* __restrict__ wdim) {
  int idx = blockIdx.x * 256 + threadIdx.x;
  if (idx >= 2048 * 64) return;
  const int n = idx >> 6, j = idx & 63;
  const int H = *hdim, W = *wdim;
  const int w = n % W;
  const int rem = n / W;
  const int h = rem % H;
  const int t = rem / H;
  float pos, i2, d;
  if (j < 22)      { pos = (float)t; i2 = (float)(2 * j);        d = 44.f; }
  else if (j < 43) { pos = (float)h; i2 = (float)(2 * (j - 22)); d = 42.f; }
  else             { pos = (float)w; i2 = (float)(2 * (j - 43)); d = 42.f; }
  const float ang = pos * powf(10000.0f, -i2 / d);
  cosT[idx] = cosf(ang);
  sinT[idx] = sinf(ang);
}

// ============ 3a. 256x256 4-phase/K-tile GEMM, m201-style (T2+T3+T4+T5) ======
// C[M][N] = A[M][K]*B[N][K]^T + bias. BK=64, K-half dbuf: 8 LDS slots of 16KB
// (A/B [buf][ks]); counted vmcnt(4) twice per tile; 2-way-free XOR layout.
// Requires M%256==0, N%256==0, K%64==0, K/64>=2, grid%8==0.
__global__ __launch_bounds__(512, 2) void k_gemm256(const unsigned short* __restrict__ A,
                                                    const unsigned short* __restrict__ B,
                                                    const float* __restrict__ bias,
                                                    float* __restrict__ C,
                                                    int M, int N, int K) {
  __shared__ __align__(16) char lds[131072];
  const int tid = threadIdx.x;
  const int lane = tid & 63;
  const int wid = tid >> 6;
  const int wr = wid >> 2, wc = wid & 3;      // 2 (M) x 4 (N) wave grid

  const int nbx = N >> 8;
  const int cpx = gridDim.x >> 3;
  const int swz = (blockIdx.x & 7) * cpx + (blockIdx.x >> 3);
  const int by = swz / nbx, bx = swz % nbx;
  const int row0 = by * 256, col0 = bx * 256;
  const int NT = K >> 6;

  // Stage one 16KB slot (256 rows x 32 k-elems): 2 gloads/thread, linear dest,
  // inverse-permuted source. phys(r,kb) = (r>>1)*128 + (((r&1)*64+kb)^(((r>>1)&7)<<4))
  auto stage_slot = [&](const unsigned short* src, int grow0, int kcol0, char* slot) {
#pragma unroll
    for (int r = 0; r < 2; ++r) {
      const int off = r * 8192 + tid * 16;
      const int pair = off >> 7;
      const int un = (off & 127) ^ ((pair & 7) << 4);
      const int grow = pair * 2 + (un >> 6);
      gload_lds16(src + (size_t)(grow0 + grow) * K + kcol0 + ((un & 63) >> 1),
                  slot + r * 8192 + wid * 1024);
    }
  };
  auto frag = [&](const char* slot, int r, int kb) -> bf16x8 {
    return *reinterpret_cast<const bf16x8*>(
        slot + (r >> 1) * 128 + ((((r & 1) << 6) + kb) ^ (((r >> 1) & 7) << 4)));
  };

  f32x4 acc[8][4];
#pragma unroll
  for (int i = 0; i < 8; ++i)
#pragma unroll
    for (int j = 0; j < 4; ++j) acc[i][j] = (f32x4){0.f, 0.f, 0.f, 0.f};

  // Prologue: tile 0 -> buf 0, order A0,B0,A1,B1; vmcnt(4) completes A0,B0.
  stage_slot(A, row0, 0,  lds);
  stage_slot(B, col0, 0,  lds + 65536);
  stage_slot(A, row0, 32, lds + 16384);
  stage_slot(B, col0, 32, lds + 65536 + 16384);
  asm volatile("s_waitcnt vmcnt(4)" ::: "memory");
  __builtin_amdgcn_s_barrier();

  const int kb = (lane >> 4) << 4;
  for (int j = 0; j < NT; ++j) {
    const int b = j & 1, bp = b ^ 1;
    const char* A0 = lds + (2 * b + 0) * 16384;
    const char* A1 = lds + (2 * b + 1) * 16384;
    const char* B0 = lds + 65536 + (2 * b + 0) * 16384;
    const char* B1 = lds + 65536 + (2 * b + 1) * 16384;
    char* pA0 = lds + (2 * bp + 0) * 16384;
    char* pA1 = lds + (2 * bp + 1) * 16384;
    char* pB0 = lds + 65536 + (2 * bp + 0) * 16384;
    char* pB1 = lds + 65536 + (2 * bp + 1) * 16384;
    const bool pf = (j + 1 < NT);
    const int kn = (j + 1) * 64;
    bf16x8 af[8], bq[2];

    // ---- ph1: ks0, cf 0-1 ----
#pragma unroll
    for (int rf = 0; rf < 8; ++rf) af[rf] = frag(A0, wr * 128 + rf * 16 + (lane & 15), kb);
#pragma unroll
    for (int cf = 0; cf < 2; ++cf) bq[cf] = frag(B0, wc * 64 + cf * 16 + (lane & 15), kb);
    if (pf) stage_slot(A, row0, kn, pA0);
    __builtin_amdgcn_s_barrier();
    __builtin_amdgcn_s_setprio(1);
#pragma unroll
    for (int rf = 0; rf < 8; ++rf)
#pragma unroll
      for (int cf = 0; cf < 2; ++cf)
        acc[rf][cf] = __builtin_amdgcn_mfma_f32_16x16x32_bf16(af[rf], bq[cf], acc[rf][cf], 0, 0, 0);
    __builtin_amdgcn_s_setprio(0);
    __builtin_amdgcn_s_barrier();

    // ---- ph2: ks0, cf 2-3; confirm this tile's ks1 ----
#pragma unroll
    for (int cf = 0; cf < 2; ++cf) bq[cf] = frag(B0, wc * 64 + (cf + 2) * 16 + (lane & 15), kb);
    if (pf) stage_slot(B, col0, kn, pB0);
    if (pf) asm volatile("s_waitcnt vmcnt(4)" ::: "memory");
    else    asm volatile("s_waitcnt vmcnt(0)" ::: "memory");
    __builtin_amdgcn_s_barrier();
    __builtin_amdgcn_s_setprio(1);
#pragma unroll
    for (int rf = 0; rf < 8; ++rf)
#pragma unroll
      for (int cf = 0; cf < 2; ++cf)
        acc[rf][cf + 2] = __builtin_amdgcn_mfma_f32_16x16x32_bf16(af[rf], bq[cf], acc[rf][cf + 2], 0, 0, 0);
    __builtin_amdgcn_s_setprio(0);
    __builtin_amdgcn_s_barrier();

    // ---- ph3: ks1, cf 0-1 ----
#pragma unroll
    for (int rf = 0; rf < 8; ++rf) af[rf] = frag(A1, wr * 128 + rf * 16 + (lane & 15), kb);
#pragma unroll
    for (int cf = 0; cf < 2; ++cf) bq[cf] = frag(B1, wc * 64 + cf * 16 + (lane & 15), kb);
    if (pf) stage_slot(A, row0, kn + 32, pA1);
    __builtin_amdgcn_s_barrier();
    __builtin_amdgcn_s_setprio(1);
#pragma unroll
    for (int rf = 0; rf < 8; ++rf)
#pragma unroll
      for (int cf = 0; cf < 2; ++cf)
        acc[rf][cf] = __builtin_amdgcn_mfma_f32_16x16x32_bf16(af[rf], bq[cf], acc[rf][cf], 0, 0, 0);
    __builtin_amdgcn_s_setprio(0);
    __builtin_amdgcn_s_barrier();

    // ---- ph4: ks1, cf 2-3; confirm next tile's ks0 ----
#pragma unroll
    for (int cf = 0; cf < 2; ++cf) bq[cf] = frag(B1, wc * 64 + (cf + 2) * 16 + (lane & 15), kb);
    if (pf) stage_slot(B, col0, kn + 32, pB1);
    if (pf) asm volatile("s_waitcnt vmcnt(4)" ::: "memory");
    __builtin_amdgcn_s_barrier();
    __builtin_amdgcn_s_setprio(1);
#pragma unroll
    for (int rf = 0; rf < 8; ++rf)
#pragma unroll
      for (int cf = 0; cf < 2; ++cf)
        acc[rf][cf + 2] = __builtin_amdgcn_mfma_f32_16x16x32_bf16(af[rf], bq[cf], acc[rf][cf + 2], 0, 0, 0);
    __builtin_amdgcn_s_setprio(0);
    __builtin_amdgcn_s_barrier();
  }

#pragma unroll
  for (int fr = 0; fr < 8; ++fr)
#pragma unroll
    for (int fc = 0; fc < 4; ++fc) {
      const int col = col0 + wc * 64 + fc * 16 + (lane & 15);
      const float bv = bias[col];
#pragma unroll
      for (int jj = 0; jj < 4; ++jj) {
        const int row = row0 + wr * 128 + fr * 16 + (lane >> 4) * 4 + jj;
        C[(size_t)row * N + col] = acc[fr][fc][jj] + bv;
      }
    }
}

// ============ 3b. 128x128 m97-structure GEMM (proj: full 256-block grid) ====
__global__ __launch_bounds__(256) void k_gemm_bt(const unsigned short* __restrict__ A,
                                                 const unsigned short* __restrict__ B,
                                                 const float* __restrict__ bias,
                                                 float* __restrict__ C,
                                                 int M, int N, int K) {
  __shared__ __align__(16) unsigned short As[128 * 32];
  __shared__ __align__(16) unsigned short Bs[128 * 32];
  const int lane = threadIdx.x & 63;
  const int wid  = threadIdx.x >> 6;
  const int wr = wid >> 1, wc = wid & 1;
  const int rowA0 = blockIdx.y * 128;
  const int rowB0 = blockIdx.x * 128;

  f32x4 acc[4][4];
#pragma unroll
  for (int i = 0; i < 4; ++i)
#pragma unroll
    for (int j = 0; j < 4; ++j) acc[i][j] = (f32x4){0.f, 0.f, 0.f, 0.f};

  for (int kt = 0; kt < K; kt += 32) {
#pragma unroll
    for (int i = 0; i < 2; ++i) {
      const int c = i * 4 + wid;
      const int off = c * 1024 + lane * 16;
      const int row = off >> 6;
      const int col = (off & 63) >> 1;
      gload_lds16(A + (size_t)(rowA0 + row) * K + kt + col, (char*)As + c * 1024);
      gload_lds16(B + (size_t)(rowB0 + row) * K + kt + col, (char*)Bs + c * 1024);
    }
    __syncthreads();
    bf16x8 af[4], bfr[4];
#pragma unroll
    for (int mi = 0; mi < 4; ++mi)
      af[mi] = *reinterpret_cast<const bf16x8*>(
          &As[(wr * 64 + mi * 16 + (lane & 15)) * 32 + (lane >> 4) * 8]);
#pragma unroll
    for (int ni = 0; ni < 4; ++ni)
      bfr[ni] = *reinterpret_cast<const bf16x8*>(
          &Bs[(wc * 64 + ni * 16 + (lane & 15)) * 32 + (lane >> 4) * 8]);
#pragma unroll
    for (int mi = 0; mi < 4; ++mi)
#pragma unroll
      for (int ni = 0; ni < 4; ++ni)
        acc[mi][ni] = __builtin_amdgcn_mfma_f32_16x16x32_bf16(af[mi], bfr[ni], acc[mi][ni], 0, 0, 0);
    __syncthreads();
  }

#pragma unroll
  for (int mi = 0; mi < 4; ++mi)
#pragma unroll
    for (int ni = 0; ni < 4; ++ni) {
      const int col = rowB0 + wc * 64 + ni * 16 + (lane & 15);
      const float b = bias[col];
#pragma unroll
      for (int j = 0; j < 4; ++j) {
        const int row = rowA0 + wr * 64 + mi * 16 + (lane >> 4) * 4 + j;
        C[(size_t)row * N + col] = acc[mi][ni][j] + b;
      }
    }
}

// ============ 4a. q/k: RMSNorm + RoPE + (q: fold softmax scale) -> bf16 [h][n][d]
__global__ __launch_bounds__(256) void k_qk_post(const float* __restrict__ qkv,
                                                 const float* __restrict__ qw,
                                                 const float* __restrict__ kw,
                                                 const float* __restrict__ cosT,
                                                 const float* __restrict__ sinT,
                                                 unsigned short* __restrict__ qo,
                                                 unsigned short* __restrict__ ko) {
  const int lane = threadIdx.x & 63;
  const int wid = threadIdx.x >> 6;
  const int pair = blockIdx.x * 4 + wid;  // (n,h)
  const int n = pair >> 4, h = pair & 15;
  const float c = cosT[n * 64 + lane];
  const float s = sinT[n * 64 + lane];
#pragma unroll
  for (int sq = 0; sq < 2; ++sq) {
    const float* src = qkv + (size_t)n * 6144 + sq * 2048 + h * 128;
    float2 v = reinterpret_cast<const float2*>(src)[lane];
    float ss = v.x * v.x + v.y * v.y;
#pragma unroll
    for (int m = 1; m < 64; m <<= 1) ss += __shfl_xor(ss, m, 64);
    const float r = rsqrtf(ss * (1.0f / 128.0f) + 1e-6f);
    float2 wv = reinterpret_cast<const float2*>(sq == 0 ? qw : kw)[lane];
    const float xr = v.x * r * wv.x;
    const float xi = v.y * r * wv.y;
    float orr = xr * c - xi * s;
    float oi  = xr * s + xi * c;
    if (sq == 0) { orr *= 0.08838834764831845f; oi *= 0.08838834764831845f; }
    unsigned short* dst = (sq == 0 ? qo : ko) + ((size_t)h * 2048 + n) * 128 + 2 * lane;
    const unsigned int pk = (unsigned int)f2bf(orr) | ((unsigned int)f2bf(oi) << 16);
    *reinterpret_cast<unsigned int*>(dst) = pk;
  }
}

// ============ 4b. v transpose: fp32 -> vt[h][d][n] bf16 ============
__global__ __launch_bounds__(256) void k_v_tr(const float* __restrict__ qkv,
                                              unsigned short* __restrict__ vt) {
  __shared__ __align__(16) unsigned short tile[64][130];
  const int h = blockIdx.y;
  const int n0 = blockIdx.x * 64;
  const int t = threadIdx.x;
  {
    const int row = t >> 2;
    const int c0 = (t & 3) * 32;
    const float* src = qkv + (size_t)(n0 + row) * 6144 + 4096 + h * 128 + c0;
#pragma unroll
    for (int j = 0; j < 32; j += 4) {
      float4 v = reinterpret_cast<const float4*>(src + j)[0];
      tile[row][c0 + j + 0] = f2bf(v.x);
      tile[row][c0 + j + 1] = f2bf(v.y);
      tile[row][c0 + j + 2] = f2bf(v.z);
      tile[row][c0 + j + 3] = f2bf(v.w);
    }
  }
  __syncthreads();
  {
    const int d = t >> 1;
    const int nc = (t & 1) * 32;
    unsigned short* dst = vt + ((size_t)h * 128 + d) * 2048 + n0 + nc;
#pragma unroll
    for (int j = 0; j < 32; j += 8) {
      bf16x8 o;
#pragma unroll
      for (int jj = 0; jj < 8; ++jj) o[jj] = (short)tile[nc + j + jj][d];
      *reinterpret_cast<bf16x8*>(dst + j) = o;
    }
  }
}

// ============ 5. flash attention (swapped QK^T, in-lane softmax, dbuf staging)
__global__ __launch_bounds__(256) void k_fattn(const unsigned short* __restrict__ q,
                                               const unsigned short* __restrict__ k,
                                               const unsigned short* __restrict__ vt,
                                               unsigned short* __restrict__ out) {
  __shared__ __align__(16) unsigned short Ks[2][64 * 128];
  __shared__ __align__(16) unsigned short Vs[2][128 * 64];
  __shared__ __align__(16) unsigned short Ps[4][16][72];
  const int lane = threadIdx.x & 63;
  const int wid = threadIdx.x >> 6;
  const int h = blockIdx.x & 15;
  const int qb = blockIdx.x >> 4;
  const int q0 = qb * 64 + wid * 16;

  auto stage = [&](int buf, int kt) {
#pragma unroll
    for (int i = 0; i < 4; ++i) {
      const int c = i * 4 + wid;
      const int off = c * 1024 + lane * 16;
      const int krow = off >> 8;
      const int kcb = (off & 255) ^ ((krow & 7) << 4);
      gload_lds16(k + ((size_t)h * 2048 + kt * 64 + krow) * 128 + (kcb >> 1),
                  (char*)Ks[buf] + c * 1024);
      const int vrow = off >> 7;
      const int vcb = (off & 127) ^ ((vrow & 7) << 4);
      gload_lds16(vt + ((size_t)h * 128 + vrow) * 2048 + kt * 64 + (vcb >> 1),
                  (char*)Vs[buf] + c * 1024);
    }
  };

  bf16x8 qf[4];
  {
    const unsigned short* qp = q + ((size_t)h * 2048 + q0 + (lane & 15)) * 128 + (lane >> 4) * 8;
#pragma unroll
    for (int kc = 0; kc < 4; ++kc) qf[kc] = *reinterpret_cast<const bf16x8*>(qp + kc * 32);
  }
  f32x4 O[8];
#pragma unroll
  for (int i = 0; i < 8; ++i) O[i] = (f32x4){0.f, 0.f, 0.f, 0.f};
  float m = -1e30f, l = 0.f;

  stage(0, 0);
  __syncthreads();

  for (int kt = 0; kt < 32; ++kt) {
    const int cur = kt & 1;
    if (kt < 31) stage(cur ^ 1, kt + 1);

    f32x4 sf[4];
    __builtin_amdgcn_s_setprio(1);
#pragma unroll
    for (int ni = 0; ni < 4; ++ni) {
      f32x4 a = (f32x4){0.f, 0.f, 0.f, 0.f};
      const int key = ni * 16 + (lane & 15);
#pragma unroll
      for (int kc = 0; kc < 4; ++kc) {
        const int db = (kc * 64 + (lane >> 4) * 16) ^ ((key & 7) << 4);
        bf16x8 af = *reinterpret_cast<const bf16x8*>((const char*)Ks[cur] + key * 256 + db);
        a = __builtin_amdgcn_mfma_f32_16x16x32_bf16(af, qf[kc], a, 0, 0, 0);
      }
      sf[ni] = a;
    }
    __builtin_amdgcn_s_setprio(0);

    float mt = fmaxf(fmaxf(sf[0][0], sf[0][1]), fmaxf(sf[0][2], sf[0][3]));
#pragma unroll
    for (int ni = 1; ni < 4; ++ni)
      mt = fmaxf(mt, fmaxf(fmaxf(sf[ni][0], sf[ni][1]), fmaxf(sf[ni][2], sf[ni][3])));
    mt = fmaxf(mt, __shfl_xor(mt, 16, 64));
    mt = fmaxf(mt, __shfl_xor(mt, 32, 64));

    if (!__all(mt <= m + 8.0f)) {
      const float mn = fmaxf(m, mt);
      const float al = __expf(m - mn);
      m = mn;
      l *= al;
#pragma unroll
      for (int dc = 0; dc < 8; ++dc)
#pragma unroll
        for (int j = 0; j < 4; ++j) O[dc][j] *= al;
    }
    float rs = 0.f;
#pragma unroll
    for (int ni = 0; ni < 4; ++ni)
#pragma unroll
      for (int j = 0; j < 4; ++j) {
        const float p = __expf(sf[ni][j] - m);
        sf[ni][j] = p;
        rs += p;
      }
    rs += __shfl_xor(rs, 16, 64);
    rs += __shfl_xor(rs, 32, 64);
    l += rs;

#pragma unroll
    for (int ni = 0; ni < 4; ++ni) {
      ushort4 pk;
      pk.x = f2bf(sf[ni][0]); pk.y = f2bf(sf[ni][1]);
      pk.z = f2bf(sf[ni][2]); pk.w = f2bf(sf[ni][3]);
      *reinterpret_cast<ushort4*>(&Ps[wid][lane & 15][ni * 16 + (lane >> 4) * 4]) = pk;
    }
    bf16x8 pa[2];
#pragma unroll
    for (int ks = 0; ks < 2; ++ks)
      pa[ks] = *reinterpret_cast<const bf16x8*>(&Ps[wid][lane & 15][ks * 32 + (lane >> 4) * 8]);

    __builtin_amdgcn_s_setprio(1);
#pragma unroll
    for (int dc = 0; dc < 8; ++dc) {
      const int d = dc * 16 + (lane & 15);
#pragma unroll
      for (int ks = 0; ks < 2; ++ks) {
        const int kb2 = (ks * 64 + (lane >> 4) * 16) ^ ((d & 7) << 4);
        bf16x8 af = *reinterpret_cast<const bf16x8*>((const char*)Vs[cur] + d * 128 + kb2);
        O[dc] = __builtin_amdgcn_mfma_f32_16x16x32_bf16(af, pa[ks], O[dc], 0, 0, 0);
      }
    }
    __builtin_amdgcn_s_setprio(0);
    __syncthreads();
  }

  const float rl = 1.0f / l;
  const int qrow = q0 + (lane & 15);
#pragma unroll
  for (int dc = 0; dc < 8; ++dc) {
    ushort4 o;
    o.x = f2bf(O[dc][0] * rl); o.y = f2bf(O[dc][1] * rl);
    o.z = f2bf(O[dc][2] * rl); o.w = f2bf(O[dc][3] * rl);
    *reinterpret_cast<ushort4*>(
        &out[(size_t)qrow * 2048 + h * 128 + dc * 16 + (lane >> 4) * 4]) = o;
  }
}

extern "C" void kernel_launch(void* const* d_in, const int* in_sizes, int n_in,
                              void* d_out, int out_size, void* d_ws, size_t ws_size,
                              hipStream_t stream) {
  (void)in_sizes; (void)n_in; (void)out_size; (void)ws_size;
  const float* x      = (const float*)d_in[0];
  const float* qkv_w  = (const float*)d_in[1];
  const float* qkv_b  = (const float*)d_in[2];
  const float* proj_w = (const float*)d_in[3];
  const float* proj_b = (const float*)d_in[4];
  const float* q_nw   = (const float*)d_in[5];
  const float* k_nw   = (const float*)d_in[6];
  const int* h_dim    = (const int*)d_in[8];
  const int* w_dim    = (const int*)d_in[9];
  float* out = (float*)d_out;

  char* ws = (char*)d_ws;
  size_t off = 0;
  auto carve = [&](size_t bytes) -> void* {
    void* p = ws + off;
    off += (bytes + 255) & ~(size_t)255;
    return p;
  };
  unsigned short* x_bf   = (unsigned short*)carve(2048ull * 2048 * 2);
  unsigned short* w1_bf  = (unsigned short*)carve(6144ull * 2048 * 2);
  unsigned short* w2_bf  = (unsigned short*)carve(2048ull * 2048 * 2);
  float*          qkvf   = (float*)carve(2048ull * 6144 * 4);
  unsigned short* q_bf   = (unsigned short*)carve(16ull * 2048 * 128 * 2);
  unsigned short* k_bf   = (unsigned short*)carve(16ull * 2048 * 128 * 2);
  unsigned short* vt_bf  = (unsigned short*)carve(16ull * 2048 * 128 * 2);
  unsigned short* att_bf = (unsigned short*)carve(2048ull * 2048 * 2);
  float*          cosT   = (float*)carve(2048ull * 64 * 4);
  float*          sinT   = (float*)carve(2048ull * 64 * 4);

  hipLaunchKernelGGL(k_cvt_bf16, dim3(2048), dim3(256), 0, stream, x, x_bf, 2048 * 2048 / 4);
  hipLaunchKernelGGL(k_cvt_bf16, dim3(2048), dim3(256), 0, stream, qkv_w, w1_bf, 6144 * 2048 / 4);
  hipLaunchKernelGGL(k_cvt_bf16, dim3(2048), dim3(256), 0, stream, proj_w, w2_bf, 2048 * 2048 / 4);
  hipLaunchKernelGGL(k_rope_tab, dim3(512), dim3(256), 0, stream, cosT, sinT, h_dim, w_dim);
  // QKV: M=2048, N=6144 -> 8x24 = 192 blocks of 512 threads (256^2 tiles)
  hipLaunchKernelGGL(k_gemm256, dim3(192), dim3(512), 0, stream,
                     x_bf, w1_bf, qkv_b, qkvf, 2048, 6144, 2048);
  hipLaunchKernelGGL(k_qk_post, dim3(8192), dim3(256), 0, stream,
                     qkvf, q_nw, k_nw, cosT, sinT, q_bf, k_bf);
  hipLaunchKernelGGL(k_v_tr, dim3(32, 16), dim3(256), 0, stream, qkvf, vt_bf);
  hipLaunchKernelGGL(k_fattn, dim3(512), dim3(256), 0, stream, q_bf, k_bf, vt_bf, att_bf);
  hipLaunchKernelGGL(k_gemm_bt, dim3(16, 16), dim3(256), 0, stream,
                     att_bf, w2_bf, proj_b, out, 2048, 2048, 2048);
}